// Round 1
// baseline (581.264 us; speedup 1.0000x reference)
//
#include <hip/hip_runtime.h>
#include <hip/hip_bf16.h>

typedef __attribute__((ext_vector_type(4))) float f32x4;
typedef __attribute__((ext_vector_type(8))) short bf16x8;

__device__ __forceinline__ unsigned short f2bf(float f) {
    union { float f; unsigned u; } v; v.f = f;
    unsigned u = v.u;
    unsigned r = (u + 0x7FFFu + ((u >> 16) & 1u)) >> 16;
    return (unsigned short)r;
}

// ---------------- LayerNorm: fp32 in -> bf16 out -------------------
__global__ __launch_bounds__(256) void ln_kernel(
    const float* __restrict__ x, const float* __restrict__ scale,
    const float* __restrict__ bias, unsigned short* __restrict__ out)
{
    int row = blockIdx.x;
    const float* xr = x + (size_t)row * 1024;
    int t = threadIdx.x;
    float4 v = ((const float4*)xr)[t];
    float s  = v.x + v.y + v.z + v.w;
    float ss = v.x*v.x + v.y*v.y + v.z*v.z + v.w*v.w;
    #pragma unroll
    for (int m = 32; m; m >>= 1) { s += __shfl_down(s, m); ss += __shfl_down(ss, m); }
    __shared__ float red[8];
    int wid = t >> 6;
    if ((t & 63) == 0) { red[wid*2] = s; red[wid*2+1] = ss; }
    __syncthreads();
    s  = red[0] + red[2] + red[4] + red[6];
    ss = red[1] + red[3] + red[5] + red[7];
    float mu  = s * (1.0f/1024.0f);
    float var = ss * (1.0f/1024.0f) - mu*mu;
    float inv = rsqrtf(var + 1e-6f);
    float4 sc = ((const float4*)scale)[t];
    float4 bi = ((const float4*)bias)[t];
    ushort4 o;
    o.x = f2bf((v.x - mu)*inv*sc.x + bi.x);
    o.y = f2bf((v.y - mu)*inv*sc.y + bi.y);
    o.z = f2bf((v.z - mu)*inv*sc.z + bi.z);
    o.w = f2bf((v.w - mu)*inv*sc.w + bi.w);
    ((ushort4*)(out + (size_t)row * 1024))[t] = o;
}

// ---------------- Weight transpose: fp32 [K][N] -> bf16 [N][K] -----
__global__ __launch_bounds__(256) void transpose_kernel(
    const float* __restrict__ W, unsigned short* __restrict__ Wt, int K, int N)
{
    __shared__ float tile[32][33];
    int n0 = blockIdx.x * 32, k0 = blockIdx.y * 32;
    int tx = threadIdx.x, ty = threadIdx.y;
    #pragma unroll
    for (int j = 0; j < 32; j += 8)
        tile[ty + j][tx] = W[(size_t)(k0 + ty + j) * N + n0 + tx];
    __syncthreads();
    #pragma unroll
    for (int j = 0; j < 32; j += 8)
        Wt[(size_t)(n0 + ty + j) * K + k0 + tx] = f2bf(tile[tx][ty + j]);
}

// ---------------- GEMM: C = A[M,K](bf16) @ Bt[N,K](bf16)^T + bias --
// EPI 0: bf16 out.  EPI 1: fp32 out + residual.  EPI 2: gelu -> bf16 out.
template<int EPI>
__global__ __launch_bounds__(256) void gemm_kernel(
    const unsigned short* __restrict__ A,
    const unsigned short* __restrict__ Bt,
    const float* __restrict__ bias,
    const float* __restrict__ res,
    void* __restrict__ out,
    int M, int N, int K)
{
    __shared__ unsigned short Al[128][72];
    __shared__ unsigned short Bl[128][72];
    int t = threadIdx.x;
    int wid = t >> 6, lane = t & 63;
    int wr = wid >> 1, wc = wid & 1;
    int l15 = lane & 15, lg = lane >> 4;
    int brow = blockIdx.y * 128, bcol = blockIdx.x * 128;
    f32x4 acc[4][4] = {};
    int srow = t >> 3;
    int skoff = (t & 7) * 8;

    for (int k0 = 0; k0 < K; k0 += 64) {
        __syncthreads();
        #pragma unroll
        for (int rr = 0; rr < 4; rr++) {
            int r = rr * 32 + srow;
            uint4 va = *(const uint4*)(A  + (size_t)(brow + r) * K + k0 + skoff);
            *(uint4*)&Al[r][skoff] = va;
            uint4 vb = *(const uint4*)(Bt + (size_t)(bcol + r) * K + k0 + skoff);
            *(uint4*)&Bl[r][skoff] = vb;
        }
        __syncthreads();
        #pragma unroll
        for (int kf = 0; kf < 2; kf++) {
            bf16x8 af[4], bfr[4];
            #pragma unroll
            for (int m = 0; m < 4; m++) af[m]  = *(const bf16x8*)&Al[wr*64 + m*16 + l15][kf*32 + lg*8];
            #pragma unroll
            for (int n = 0; n < 4; n++) bfr[n] = *(const bf16x8*)&Bl[wc*64 + n*16 + l15][kf*32 + lg*8];
            #pragma unroll
            for (int m = 0; m < 4; m++)
                #pragma unroll
                for (int n = 0; n < 4; n++)
                    acc[m][n] = __builtin_amdgcn_mfma_f32_16x16x32_bf16(af[m], bfr[n], acc[m][n], 0, 0, 0);
        }
    }

    #pragma unroll
    for (int m = 0; m < 4; m++) {
        #pragma unroll
        for (int n = 0; n < 4; n++) {
            int col = bcol + wc*64 + n*16 + l15;
            float bs = bias[col];
            #pragma unroll
            for (int r = 0; r < 4; r++) {
                int row = brow + wr*64 + m*16 + lg*4 + r;
                size_t idx = (size_t)row * N + col;
                float v = acc[m][n][r] + bs;
                if (EPI == 0) {
                    ((unsigned short*)out)[idx] = f2bf(v);
                } else if (EPI == 1) {
                    ((float*)out)[idx] = v + res[idx];
                } else {
                    float g = 0.5f * v * (1.0f + tanhf(0.7978845608028654f * (v + 0.044715f * v * v * v)));
                    ((unsigned short*)out)[idx] = f2bf(g);
                }
            }
        }
    }
}

// ---------------- Flash attention -------------------------------
// qkv: bf16 [B*S][3072]; layout col = t*1024 + h*64 + d (t=0:q,1:k,2:v)
// ctx: bf16 [B*S][1024], col = h*64 + d
__global__ __launch_bounds__(256) void attn_kernel(
    const unsigned short* __restrict__ qkv, unsigned short* __restrict__ ctx)
{
    __shared__ unsigned short Kl[64][72];
    __shared__ unsigned short Vt[64][72];
    __shared__ unsigned short Pl[4][32][72];

    int bh = blockIdx.y;
    int b = bh >> 4, h = bh & 15;
    int qt = blockIdx.x;
    int t = threadIdx.x, wid = t >> 6, lane = t & 63;
    int l15 = lane & 15, lg = lane >> 4;
    const size_t base = (size_t)b * 2048 * 3072 + (size_t)h * 64;

    // Q fragments (held whole loop)
    bf16x8 qf[2][2];
    int qr0 = qt * 128 + wid * 32;
    #pragma unroll
    for (int m = 0; m < 2; m++)
        #pragma unroll
        for (int kf = 0; kf < 2; kf++)
            qf[m][kf] = *(const bf16x8*)(qkv + base + (size_t)(qr0 + m*16 + l15) * 3072 + kf*32 + lg*8);

    f32x4 o[2][4] = {};
    float mrun[2][4], lrun[2][4];
    #pragma unroll
    for (int m = 0; m < 2; m++)
        #pragma unroll
        for (int r = 0; r < 4; r++) { mrun[m][r] = -1e30f; lrun[m][r] = 0.0f; }

    int skey = t >> 2;
    int sdg = (t & 3) * 16;

    for (int kt = 0; kt < 32; kt++) {
        __syncthreads();
        int key0 = kt * 64;
        // stage K [key][dim]
        const unsigned short* kp = qkv + base + 1024 + (size_t)(key0 + skey) * 3072 + sdg;
        *(uint4*)&Kl[skey][sdg]     = *(const uint4*)kp;
        *(uint4*)&Kl[skey][sdg + 8] = *(const uint4*)(kp + 8);
        // stage V transposed: Vt[dim][key]
        const unsigned short* vp = qkv + base + 2048 + (size_t)(key0 + skey) * 3072 + sdg;
        union { uint4 v[2]; unsigned short u[16]; } vv;
        vv.v[0] = *(const uint4*)vp;
        vv.v[1] = *(const uint4*)(vp + 8);
        #pragma unroll
        for (int j = 0; j < 16; j++) Vt[sdg + j][skey] = vv.u[j];
        __syncthreads();

        // S = Q K^T  (rows=q, cols=key)
        f32x4 sa[2][4] = {};
        #pragma unroll
        for (int kf = 0; kf < 2; kf++) {
            bf16x8 kfr[4];
            #pragma unroll
            for (int n = 0; n < 4; n++) kfr[n] = *(const bf16x8*)&Kl[n*16 + l15][kf*32 + lg*8];
            #pragma unroll
            for (int m = 0; m < 2; m++)
                #pragma unroll
                for (int n = 0; n < 4; n++)
                    sa[m][n] = __builtin_amdgcn_mfma_f32_16x16x32_bf16(qf[m][kf], kfr[n], sa[m][n], 0, 0, 0);
        }

        // online softmax (scale = 1/8)
        #pragma unroll
        for (int m = 0; m < 2; m++) {
            float pm[4];
            #pragma unroll
            for (int r = 0; r < 4; r++) {
                float v = -1e30f;
                #pragma unroll
                for (int n = 0; n < 4; n++) v = fmaxf(v, sa[m][n][r]);
                pm[r] = v * 0.125f;
            }
            #pragma unroll
            for (int msk = 1; msk < 16; msk <<= 1)
                #pragma unroll
                for (int r = 0; r < 4; r++) pm[r] = fmaxf(pm[r], __shfl_xor(pm[r], msk));
            float corr[4];
            #pragma unroll
            for (int r = 0; r < 4; r++) {
                float mn = fmaxf(mrun[m][r], pm[r]);
                corr[r] = __expf(mrun[m][r] - mn);
                mrun[m][r] = mn;
            }
            float rs[4] = {0.f, 0.f, 0.f, 0.f};
            #pragma unroll
            for (int n = 0; n < 4; n++) {
                #pragma unroll
                for (int r = 0; r < 4; r++) {
                    float pv = __expf(sa[m][n][r] * 0.125f - mrun[m][r]);
                    rs[r] += pv;
                    Pl[wid][m*16 + lg*4 + r][n*16 + l15] = f2bf(pv);
                }
            }
            #pragma unroll
            for (int msk = 1; msk < 16; msk <<= 1)
                #pragma unroll
                for (int r = 0; r < 4; r++) rs[r] += __shfl_xor(rs[r], msk);
            #pragma unroll
            for (int r = 0; r < 4; r++) lrun[m][r] = lrun[m][r] * corr[r] + rs[r];
            #pragma unroll
            for (int n2 = 0; n2 < 4; n2++)
                #pragma unroll
                for (int r = 0; r < 4; r++) o[m][n2][r] *= corr[r];
        }

        // wait for this wave's Pl writes (cross-lane within wave)
        asm volatile("s_waitcnt lgkmcnt(0)" ::: "memory");
        __builtin_amdgcn_sched_barrier(0);

        // O += P V
        #pragma unroll
        for (int kf2 = 0; kf2 < 2; kf2++) {
            bf16x8 vf[4];
            #pragma unroll
            for (int n2 = 0; n2 < 4; n2++) vf[n2] = *(const bf16x8*)&Vt[n2*16 + l15][kf2*32 + lg*8];
            #pragma unroll
            for (int m = 0; m < 2; m++) {
                bf16x8 pa = *(const bf16x8*)&Pl[wid][m*16 + l15][kf2*32 + lg*8];
                #pragma unroll
                for (int n2 = 0; n2 < 4; n2++)
                    o[m][n2] = __builtin_amdgcn_mfma_f32_16x16x32_bf16(pa, vf[n2], o[m][n2], 0, 0, 0);
            }
        }
    }

    // write ctx
    size_t cbase = (size_t)b * 2048 * 1024 + (size_t)h * 64;
    #pragma unroll
    for (int m = 0; m < 2; m++)
        #pragma unroll
        for (int n2 = 0; n2 < 4; n2++)
            #pragma unroll
            for (int r = 0; r < 4; r++) {
                int qr = qr0 + m*16 + lg*4 + r;
                float val = o[m][n2][r] / lrun[m][r];
                ctx[cbase + (size_t)qr * 1024 + n2*16 + l15] = f2bf(val);
            }
}

// ---------------- launch ----------------
extern "C" void kernel_launch(void* const* d_in, const int* in_sizes, int n_in,
                              void* d_out, int out_size, void* d_ws, size_t ws_size,
                              hipStream_t stream) {
    const float* x      = (const float*)d_in[0];
    const float* ln1_s  = (const float*)d_in[1];
    const float* ln1_b  = (const float*)d_in[2];
    const float* ln2_s  = (const float*)d_in[3];
    const float* ln2_b  = (const float*)d_in[4];
    const float* qkv_w  = (const float*)d_in[5];
    const float* qkv_b  = (const float*)d_in[6];
    const float* proj_w = (const float*)d_in[7];
    const float* proj_b = (const float*)d_in[8];
    const float* fc1_w  = (const float*)d_in[9];
    const float* fc1_b  = (const float*)d_in[10];
    const float* fc2_w  = (const float*)d_in[11];
    const float* fc2_b  = (const float*)d_in[12];
    float* out = (float*)d_out;

    char* ws = (char*)d_ws;
    // layout (bytes): x1 fp32 @0 (32MB); h bf16 @32M (16MB); qkv bf16 @48M (48MB);
    // ctx bf16 @96M (16MB); gelu bf16 reuses @48M (64MB); weightT @112M (8MB)
    float*          x1   = (float*)(ws + 0);
    unsigned short* h    = (unsigned short*)(ws + (size_t)32 * 1024 * 1024);
    unsigned short* qkvb = (unsigned short*)(ws + (size_t)48 * 1024 * 1024);
    unsigned short* ctxb = (unsigned short*)(ws + (size_t)96 * 1024 * 1024);
    unsigned short* gbuf = (unsigned short*)(ws + (size_t)48 * 1024 * 1024);
    unsigned short* wT   = (unsigned short*)(ws + (size_t)112 * 1024 * 1024);

    dim3 tb(32, 8);

    // 1) qkv_w^T (1024x3072 -> 3072x1024)
    transpose_kernel<<<dim3(96, 32), tb, 0, stream>>>(qkv_w, wT, 1024, 3072);
    // 2) h = LN1(x)
    ln_kernel<<<8192, 256, 0, stream>>>(x, ln1_s, ln1_b, h);
    // 3) qkv = h @ qkv_w + b
    gemm_kernel<0><<<dim3(24, 64), 256, 0, stream>>>(h, wT, qkv_b, nullptr, qkvb, 8192, 3072, 1024);
    // 4) attention
    attn_kernel<<<dim3(16, 64), 256, 0, stream>>>(qkvb, ctxb);
    // 5) proj_w^T
    transpose_kernel<<<dim3(32, 32), tb, 0, stream>>>(proj_w, wT, 1024, 1024);
    // 6) x1 = x + ctx @ proj_w + b
    gemm_kernel<1><<<dim3(8, 64), 256, 0, stream>>>(ctxb, wT, proj_b, x, x1, 8192, 1024, 1024);
    // 7) h = LN2(x1)
    ln_kernel<<<8192, 256, 0, stream>>>(x1, ln2_s, ln2_b, h);
    // 8) fc1_w^T
    transpose_kernel<<<dim3(128, 32), tb, 0, stream>>>(fc1_w, wT, 1024, 4096);
    // 9) g = gelu(h @ fc1_w + b)
    gemm_kernel<2><<<dim3(32, 64), 256, 0, stream>>>(h, wT, fc1_b, nullptr, gbuf, 8192, 4096, 1024);
    // 10) fc2_w^T
    transpose_kernel<<<dim3(32, 128), tb, 0, stream>>>(fc2_w, wT, 4096, 1024);
    // 11) out = x1 + g @ fc2_w + b
    gemm_kernel<1><<<dim3(8, 64), 256, 0, stream>>>(gbuf, wT, fc2_b, x1, out, 8192, 1024, 4096);
}